// Round 3
// baseline (2170.127 us; speedup 1.0000x reference)
//
#include <hip/hip_runtime.h>

#define NN 50000
#define NE 800000
#define FF 64
#define EB 20
#define NBLK 3
#define NG 100

__device__ __forceinline__ float silu_f(float x) {
  return x / (1.f + expf(-x));
}

// ---------------- init ----------------
__global__ __launch_bounds__(256) void k_init(float4* v0, int* cnt, float* gout) {
  int i = blockIdx.x * blockDim.x + threadIdx.x;
  if (i < NN * 48) v0[i] = make_float4(0.f, 0.f, 0.f, 0.f);
  if (i < NN) cnt[i] = 0;
  if (i < NG) gout[i] = 0.f;
}

// embed + recv histogram (cnt zeroed by k_init in a prior launch)
__global__ __launch_bounds__(256) void k_embed(const int* __restrict__ feat,
                                               const float* __restrict__ emb,
                                               const int* __restrict__ ei,
                                               float* __restrict__ s, int* cnt) {
  int i = blockIdx.x * blockDim.x + threadIdx.x;
  if (i < NN * FF) s[i] = emb[feat[i >> 6] * FF + (i & 63)];
  if (i < NE) atomicAdd(&cnt[ei[i]], 1);
}

// ---------------- CSR scan (single block; writes rowst and rowcur copy) ----
__global__ __launch_bounds__(1024) void k_scan(const int* __restrict__ cnt,
                                               int* __restrict__ rowst,
                                               int* __restrict__ rowcur) {
  __shared__ int part[1024];
  int t = threadIdx.x;
  const int CH = 52;  // 1024*52 >= NN, multiple of 4 for int4 loads
  int base = t * CH;
  int own = 0;
  const int4* c4 = (const int4*)(cnt + base);
#pragma unroll
  for (int i = 0; i < CH / 4; i++) {
    int idx = base + i * 4;
    if (idx + 3 < NN) {
      int4 q = c4[i];
      own += q.x + q.y + q.z + q.w;
    } else {
      for (int j = 0; j < 4; j++)
        if (idx + j < NN) own += cnt[idx + j];
    }
  }
  part[t] = own;
  __syncthreads();
  for (int off = 1; off < 1024; off <<= 1) {
    int v = (t >= off) ? part[t - off] : 0;
    __syncthreads();
    part[t] += v;
    __syncthreads();
  }
  int excl = part[t] - own;
  for (int i = 0; i < CH; i++) {
    int idx = base + i;
    if (idx < NN) {
      rowst[idx] = excl;
      rowcur[idx] = excl;
      excl += cnt[idx];
    }
  }
  if (t == 1023) rowst[NN] = excl;
}

// ---------------- edge geometry (edge-parallel, coalesced writes) ----------
__global__ __launch_bounds__(256) void k_fillgeo(const int* __restrict__ ei,
                                                 const float* __restrict__ pos,
                                                 int* rowcur, float4* __restrict__ d4,
                                                 int* __restrict__ eid) {
  int e = blockIdx.x * blockDim.x + threadIdx.x;
  if (e >= NE) return;
  int rv = ei[e], sd = ei[NE + e];
  float dx = pos[sd * 3 + 0] - pos[rv * 3 + 0];
  float dy = pos[sd * 3 + 1] - pos[rv * 3 + 1];
  float dz = pos[sd * 3 + 2] - pos[rv * 3 + 2];
  float r = sqrtf(dx * dx + dy * dy + dz * dz);
  d4[e] = make_float4(dx, dy, dz, r);
  int slot = atomicAdd(&rowcur[rv], 1);
  eid[slot] = e;
}

// slot-parallel: geo=(dhat,fc), send_s, rbf2[slot][k]=rbf_k*fc  (all coalesced)
__global__ __launch_bounds__(256) void k_rbf(const int* __restrict__ ei,
                                             const float4* __restrict__ d4,
                                             const int* __restrict__ eid,
                                             float4* __restrict__ geo,
                                             int* __restrict__ send_s,
                                             float* __restrict__ rbf2) {
  __shared__ float buf[256 * EB];
  int tid = threadIdx.x;
  int slot = blockIdx.x * 256 + tid;  // NE == 3125*256 exactly
  int e = eid[slot];
  float4 d = d4[e];
  float r = d.w;
  float inv = 1.f / (r + 1e-10f);
  float fc = (r < 5.0f) ? 0.5f * (cosf(0.6283185307179586f * r) + 1.f) : 0.f;
  geo[slot] = make_float4(d.x * inv, d.y * inv, d.z * inv, fc);
  send_s[slot] = ei[NE + e];
  float cs = 0.6324555320336759f * inv * fc;
#pragma unroll
  for (int k = 0; k < EB; k++)
    buf[tid * EB + k] = cs * sinf((float)(k + 1) * 0.6283185307179586f * r);
  __syncthreads();
  size_t base = (size_t)blockIdx.x * 256 * EB;
#pragma unroll
  for (int i = 0; i < EB; i++)
    rbf2[base + i * 256 + tid] = buf[i * 256 + tid];
}

// ---------------- phi = silu(s@W1+b1)@W2+b2 ----------------
__global__ __launch_bounds__(256) void k_phi1(const float* __restrict__ s,
                                              const float* __restrict__ W1,
                                              const float* __restrict__ b1,
                                              float* __restrict__ h) {
  int lane = threadIdx.x & 63;
  int gw = (blockIdx.x * blockDim.x + threadIdx.x) >> 6;
  int nw = (gridDim.x * blockDim.x) >> 6;
  float w[FF];
#pragma unroll
  for (int k = 0; k < FF; k++) w[k] = W1[k * FF + lane];
  float bb = b1[lane];
  for (int n0 = gw; n0 < NN; n0 += nw) {
    int n = __builtin_amdgcn_readfirstlane(n0);
    const float4* row = (const float4*)(s + (size_t)n * FF);
    float a0 = bb, a1 = 0.f, a2 = 0.f, a3 = 0.f;
#pragma unroll
    for (int q = 0; q < 16; q++) {
      float4 x = row[q];
      a0 = fmaf(x.x, w[4 * q], a0);
      a1 = fmaf(x.y, w[4 * q + 1], a1);
      a2 = fmaf(x.z, w[4 * q + 2], a2);
      a3 = fmaf(x.w, w[4 * q + 3], a3);
    }
    h[(size_t)n * FF + lane] = silu_f((a0 + a1) + (a2 + a3));
  }
}

// phi3[n*64+lane] = (gate_v, gate_e, m_s) for col=lane
__global__ __launch_bounds__(256) void k_phi2(const float* __restrict__ h,
                                              const float* __restrict__ W2,
                                              const float* __restrict__ b2,
                                              float3* __restrict__ phi3) {
  int lane = threadIdx.x & 63;
  int gw = (blockIdx.x * blockDim.x + threadIdx.x) >> 6;
  int nw = (gridDim.x * blockDim.x) >> 6;
  float w0[FF], w1[FF], w2[FF];
#pragma unroll
  for (int k = 0; k < FF; k++) {
    w0[k] = W2[k * 192 + lane];
    w1[k] = W2[k * 192 + 64 + lane];
    w2[k] = W2[k * 192 + 128 + lane];
  }
  float c0 = b2[lane], c1 = b2[64 + lane], c2 = b2[128 + lane];
  for (int n0 = gw; n0 < NN; n0 += nw) {
    int n = __builtin_amdgcn_readfirstlane(n0);
    const float4* row = (const float4*)(h + (size_t)n * FF);
    float a0 = c0, a1 = c1, a2 = c2;
#pragma unroll
    for (int q = 0; q < 16; q++) {
      float4 x = row[q];
      a0 = fmaf(x.x, w0[4 * q], a0);
      a1 = fmaf(x.x, w1[4 * q], a1);
      a2 = fmaf(x.x, w2[4 * q], a2);
      a0 = fmaf(x.y, w0[4 * q + 1], a0);
      a1 = fmaf(x.y, w1[4 * q + 1], a1);
      a2 = fmaf(x.y, w2[4 * q + 1], a2);
      a0 = fmaf(x.z, w0[4 * q + 2], a0);
      a1 = fmaf(x.z, w1[4 * q + 2], a1);
      a2 = fmaf(x.z, w2[4 * q + 2], a2);
      a0 = fmaf(x.w, w0[4 * q + 3], a0);
      a1 = fmaf(x.w, w1[4 * q + 3], a1);
      a2 = fmaf(x.w, w2[4 * q + 3], a2);
    }
    phi3[(size_t)n * FF + lane] = make_float3(a0, a1, a2);
  }
}

// ---------------- message aggregation (CSR, wave-per-node) ----------------
template <bool FIRST>
__global__ __launch_bounds__(256) void k_msg(const float3* __restrict__ phi3,
                                             const float3* __restrict__ v03,
                                             float* __restrict__ s,
                                             float3* __restrict__ v13,
                                             const float* __restrict__ fW,
                                             const float* __restrict__ fb,
                                             const float4* __restrict__ geo,
                                             const int* __restrict__ send_s,
                                             const int* __restrict__ rowst,
                                             const float* __restrict__ rbf2) {
  int lane = threadIdx.x & 63;
  int gw = (blockIdx.x * blockDim.x + threadIdx.x) >> 6;
  int nw = (gridDim.x * blockDim.x) >> 6;
  float fw0[EB], fw1[EB], fw2[EB];
#pragma unroll
  for (int k = 0; k < EB; k++) {
    fw0[k] = fW[k * 192 + lane];
    fw1[k] = fW[k * 192 + 64 + lane];
    fw2[k] = fW[k * 192 + 128 + lane];
  }
  float fb0 = fb[lane], fb1 = fb[64 + lane], fb2 = fb[128 + lane];
  for (int n0 = gw; n0 < NN; n0 += nw) {
    int n = __builtin_amdgcn_readfirstlane(n0);
    int beg = rowst[n], end = rowst[n + 1];
    float accs = 0.f, av0 = 0.f, av1 = 0.f, av2 = 0.f;
    for (int slot = beg; slot < end; slot++) {
      float4 g = geo[slot];  // slot is wave-uniform
      if (g.w > 0.f) {       // fc==0 -> zero contribution (exact)
        int j = send_s[slot];
        const float4* rp = (const float4*)(rbf2 + (size_t)slot * EB);
        float4 q0 = rp[0], q1 = rp[1], q2 = rp[2], q3 = rp[3], q4 = rp[4];
        float rb[EB] = {q0.x, q0.y, q0.z, q0.w, q1.x, q1.y, q1.z, q1.w,
                        q2.x, q2.y, q2.z, q2.w, q3.x, q3.y, q3.z, q3.w,
                        q4.x, q4.y, q4.z, q4.w};
        float wf1 = fb1 * g.w, wf2 = fb2 * g.w;
#pragma unroll
        for (int k = 0; k < EB; k++) {
          wf1 = fmaf(rb[k], fw1[k], wf1);
          wf2 = fmaf(rb[k], fw2[k], wf2);
        }
        float3 pj = phi3[(size_t)j * FF + lane];
        float ge = pj.y * wf1;
        accs = fmaf(pj.z, wf2, accs);
        if (!FIRST) {
          float wf0 = fb0 * g.w;
#pragma unroll
          for (int k = 0; k < EB; k++) wf0 = fmaf(rb[k], fw0[k], wf0);
          float gv = pj.x * wf0;
          float3 vj = v03[(size_t)j * FF + lane];
          av0 = fmaf(vj.x, gv, fmaf(g.x, ge, av0));
          av1 = fmaf(vj.y, gv, fmaf(g.y, ge, av1));
          av2 = fmaf(vj.z, gv, fmaf(g.z, ge, av2));
        } else {  // v==0: gate_v term vanishes
          av0 = fmaf(g.x, ge, av0);
          av1 = fmaf(g.y, ge, av1);
          av2 = fmaf(g.z, ge, av2);
        }
      }
    }
    s[(size_t)n * FF + lane] += accs;
    if (!FIRST) {
      float3 vo = v03[(size_t)n * FF + lane];
      v13[(size_t)n * FF + lane] =
          make_float3(vo.x + av0, vo.y + av1, vo.z + av2);
    } else {
      v13[(size_t)n * FF + lane] = make_float3(av0, av1, av2);
    }
  }
}

// ---------------- update block ----------------
__global__ __launch_bounds__(256) void k_upd1(const float3* __restrict__ v13,
                                              const float* __restrict__ U,
                                              const float* __restrict__ V,
                                              float3* __restrict__ Uv3,
                                              float* __restrict__ Vn,
                                              float* __restrict__ dotUV) {
  int lane = threadIdx.x & 63;
  int gw = (blockIdx.x * blockDim.x + threadIdx.x) >> 6;
  int nw = (gridDim.x * blockDim.x) >> 6;
  float u[FF], w[FF];
#pragma unroll
  for (int k = 0; k < FF; k++) {
    u[k] = U[k * FF + lane];
    w[k] = V[k * FF + lane];
  }
  for (int n0 = gw; n0 < NN; n0 += nw) {
    int n = __builtin_amdgcn_readfirstlane(n0);
    const float4* row = (const float4*)((const float*)v13 + (size_t)n * 192);
    float uv0 = 0, uv1 = 0, uv2 = 0, vv0 = 0, vv1 = 0, vv2 = 0;
#pragma unroll
    for (int gq = 0; gq < 16; gq++) {
      float4 A = row[3 * gq], B = row[3 * gq + 1], C = row[3 * gq + 2];
      int k = 4 * gq;
      uv0 = fmaf(A.x, u[k], uv0); vv0 = fmaf(A.x, w[k], vv0);
      uv1 = fmaf(A.y, u[k], uv1); vv1 = fmaf(A.y, w[k], vv1);
      uv2 = fmaf(A.z, u[k], uv2); vv2 = fmaf(A.z, w[k], vv2);
      uv0 = fmaf(A.w, u[k + 1], uv0); vv0 = fmaf(A.w, w[k + 1], vv0);
      uv1 = fmaf(B.x, u[k + 1], uv1); vv1 = fmaf(B.x, w[k + 1], vv1);
      uv2 = fmaf(B.y, u[k + 1], uv2); vv2 = fmaf(B.y, w[k + 1], vv2);
      uv0 = fmaf(B.z, u[k + 2], uv0); vv0 = fmaf(B.z, w[k + 2], vv0);
      uv1 = fmaf(B.w, u[k + 2], uv1); vv1 = fmaf(B.w, w[k + 2], vv1);
      uv2 = fmaf(C.x, u[k + 2], uv2); vv2 = fmaf(C.x, w[k + 2], vv2);
      uv0 = fmaf(C.y, u[k + 3], uv0); vv0 = fmaf(C.y, w[k + 3], vv0);
      uv1 = fmaf(C.z, u[k + 3], uv1); vv1 = fmaf(C.z, w[k + 3], vv1);
      uv2 = fmaf(C.w, u[k + 3], uv2); vv2 = fmaf(C.w, w[k + 3], vv2);
    }
    Uv3[(size_t)n * FF + lane] = make_float3(uv0, uv1, uv2);
    Vn[(size_t)n * FF + lane] = sqrtf(vv0 * vv0 + vv1 * vv1 + vv2 * vv2 + 1e-8f);
    dotUV[(size_t)n * FF + lane] = uv0 * vv0 + uv1 * vv1 + uv2 * vv2;
  }
}

__global__ __launch_bounds__(256) void k_upd2(const float* __restrict__ s,
                                              const float* __restrict__ Vn,
                                              const float* __restrict__ W1,
                                              const float* __restrict__ b1,
                                              float* __restrict__ h) {
  int lane = threadIdx.x & 63;
  int gw = (blockIdx.x * blockDim.x + threadIdx.x) >> 6;
  int nw = (gridDim.x * blockDim.x) >> 6;
  float w[2 * FF];
#pragma unroll
  for (int k = 0; k < 2 * FF; k++) w[k] = W1[k * FF + lane];
  float bb = b1[lane];
  for (int n0 = gw; n0 < NN; n0 += nw) {
    int n = __builtin_amdgcn_readfirstlane(n0);
    const float4* rs = (const float4*)(s + (size_t)n * FF);
    const float4* rv = (const float4*)(Vn + (size_t)n * FF);
    float a0 = bb, a1 = 0.f, a2 = 0.f, a3 = 0.f;
#pragma unroll
    for (int q = 0; q < 16; q++) {
      float4 x = rs[q];
      a0 = fmaf(x.x, w[4 * q], a0);
      a1 = fmaf(x.y, w[4 * q + 1], a1);
      a2 = fmaf(x.z, w[4 * q + 2], a2);
      a3 = fmaf(x.w, w[4 * q + 3], a3);
    }
#pragma unroll
    for (int q = 0; q < 16; q++) {
      float4 x = rv[q];
      a0 = fmaf(x.x, w[FF + 4 * q], a0);
      a1 = fmaf(x.y, w[FF + 4 * q + 1], a1);
      a2 = fmaf(x.z, w[FF + 4 * q + 2], a2);
      a3 = fmaf(x.w, w[FF + 4 * q + 3], a3);
    }
    h[(size_t)n * FF + lane] = silu_f((a0 + a1) + (a2 + a3));
  }
}

__global__ __launch_bounds__(256) void k_upd3(const float* __restrict__ h,
                                              const float* __restrict__ W2,
                                              const float* __restrict__ b2,
                                              const float3* __restrict__ Uv3,
                                              const float3* __restrict__ v13,
                                              const float* __restrict__ dotUV,
                                              float3* __restrict__ v03,
                                              float* __restrict__ s) {
  int lane = threadIdx.x & 63;
  int gw = (blockIdx.x * blockDim.x + threadIdx.x) >> 6;
  int nw = (gridDim.x * blockDim.x) >> 6;
  float w0[FF], w1[FF], w2[FF];
#pragma unroll
  for (int k = 0; k < FF; k++) {
    w0[k] = W2[k * 192 + lane];
    w1[k] = W2[k * 192 + 64 + lane];
    w2[k] = W2[k * 192 + 128 + lane];
  }
  float c0 = b2[lane], c1 = b2[64 + lane], c2 = b2[128 + lane];
  for (int n0 = gw; n0 < NN; n0 += nw) {
    int n = __builtin_amdgcn_readfirstlane(n0);
    const float4* row = (const float4*)(h + (size_t)n * FF);
    float a0 = c0, a1 = c1, a2 = c2;
#pragma unroll
    for (int q = 0; q < 16; q++) {
      float4 x = row[q];
      a0 = fmaf(x.x, w0[4 * q], a0);
      a1 = fmaf(x.x, w1[4 * q], a1);
      a2 = fmaf(x.x, w2[4 * q], a2);
      a0 = fmaf(x.y, w0[4 * q + 1], a0);
      a1 = fmaf(x.y, w1[4 * q + 1], a1);
      a2 = fmaf(x.y, w2[4 * q + 1], a2);
      a0 = fmaf(x.z, w0[4 * q + 2], a0);
      a1 = fmaf(x.z, w1[4 * q + 2], a1);
      a2 = fmaf(x.z, w2[4 * q + 2], a2);
      a0 = fmaf(x.w, w0[4 * q + 3], a0);
      a1 = fmaf(x.w, w1[4 * q + 3], a1);
      a2 = fmaf(x.w, w2[4 * q + 3], a2);
    }
    float3 uv = Uv3[(size_t)n * FF + lane];
    float3 vv = v13[(size_t)n * FF + lane];
    v03[(size_t)n * FF + lane] = make_float3(
        fmaf(a0, uv.x, vv.x), fmaf(a0, uv.y, vv.y), fmaf(a0, uv.z, vv.z));
    size_t i_ = (size_t)n * FF + lane;
    s[i_] = fmaf(a1, dotUV[i_], s[i_] + a2);
  }
}

// ---------------- fused readout + graph sum + laplacian ----------------
__global__ __launch_bounds__(256) void k_final(const float* __restrict__ s,
                                               const float* __restrict__ roW1,
                                               const float* __restrict__ rob1,
                                               const float* __restrict__ roW2,
                                               const float* __restrict__ rob2,
                                               const int* __restrict__ gidx,
                                               const int* __restrict__ rowst,
                                               const int* __restrict__ send_s,
                                               float* __restrict__ gout,
                                               float* __restrict__ lap) {
  int lane = threadIdx.x & 63;
  int gw = (blockIdx.x * blockDim.x + threadIdx.x) >> 6;
  int nw = (gridDim.x * blockDim.x) >> 6;
  float w[FF];
#pragma unroll
  for (int k = 0; k < FF; k++) w[k] = roW1[k * FF + lane];
  float b1v = rob1[lane], w2v = roW2[lane], b2v = rob2[0];
  for (int n0 = gw; n0 < NN; n0 += nw) {
    int n = __builtin_amdgcn_readfirstlane(n0);
    int beg = rowst[n], end = rowst[n + 1];
    float acc = 0.f;
    for (int slot = beg; slot < end; slot++) {
      int j = send_s[slot];
      acc += s[(size_t)j * FF + lane];
    }
    float sv = s[(size_t)n * FF + lane];
    lap[(size_t)n * FF + lane] = (float)(end - beg) * sv - acc;
    const float4* row = (const float4*)(s + (size_t)n * FF);
    float a0 = b1v, a1 = 0.f, a2 = 0.f, a3 = 0.f;
#pragma unroll
    for (int q = 0; q < 16; q++) {
      float4 x = row[q];
      a0 = fmaf(x.x, w[4 * q], a0);
      a1 = fmaf(x.y, w[4 * q + 1], a1);
      a2 = fmaf(x.z, w[4 * q + 2], a2);
      a3 = fmaf(x.w, w[4 * q + 3], a3);
    }
    float c = silu_f((a0 + a1) + (a2 + a3)) * w2v;
#pragma unroll
    for (int off = 32; off > 0; off >>= 1) c += __shfl_down(c, off, 64);
    if (lane == 0) atomicAdd(&gout[gidx[n]], c + b2v);
  }
}

extern "C" void kernel_launch(void* const* d_in, const int* in_sizes, int n_in,
                              void* d_out, int out_size, void* d_ws, size_t ws_size,
                              hipStream_t stream) {
  const int* feat = (const int*)d_in[0];
  const float* pos = (const float*)d_in[1];
  const int* ei = (const int*)d_in[2];
  const int* gidx = (const int*)d_in[3];
  const float* emb = (const float*)d_in[4];
  const float* msgW1 = (const float*)d_in[5];
  const float* msgb1 = (const float*)d_in[6];
  const float* msgW2 = (const float*)d_in[7];
  const float* msgb2 = (const float*)d_in[8];
  const float* filtW = (const float*)d_in[9];
  const float* filtb = (const float*)d_in[10];
  const float* updU = (const float*)d_in[11];
  const float* updV = (const float*)d_in[12];
  const float* updW1 = (const float*)d_in[13];
  const float* updb1 = (const float*)d_in[14];
  const float* updW2 = (const float*)d_in[15];
  const float* updb2 = (const float*)d_in[16];
  const float* roW1 = (const float*)d_in[17];
  const float* rob1 = (const float*)d_in[18];
  const float* roW2 = (const float*)d_in[19];
  const float* rob2 = (const float*)d_in[20];

  float* gout = (float*)d_out;
  float* s = gout + NG;
  float* lap = s + (size_t)NN * FF;

  char* p = (char*)d_ws;
  auto alloc = [&](size_t bytes) {
    char* r = p;
    p += (bytes + 255) & ~(size_t)255;
    return r;
  };
  float3* v03 = (float3*)alloc((size_t)NN * 192 * 4);
  float3* v13 = (float3*)alloc((size_t)NN * 192 * 4);
  float3* phiUv3 = (float3*)alloc((size_t)NN * 192 * 4);  // phi, reused as Uv
  float* h = (float*)alloc((size_t)NN * FF * 4);
  float* Vn = (float*)alloc((size_t)NN * FF * 4);
  float* dotUV = (float*)alloc((size_t)NN * FF * 4);
  float4* geo = (float4*)alloc((size_t)NE * 16);
  float4* d4 = (float4*)alloc((size_t)NE * 16);
  float* rbf2 = (float*)alloc((size_t)NE * EB * 4);
  int* send_s = (int*)alloc((size_t)NE * 4);
  int* eid = (int*)alloc((size_t)NE * 4);
  int* rowst = (int*)alloc((size_t)(NN + 1) * 4);
  int* rowcur = (int*)alloc((size_t)NN * 4);
  int* cnt = (int*)alloc((size_t)NN * 4);

  k_init<<<(NN * 48 + 255) / 256, 256, 0, stream>>>((float4*)v03, cnt, gout);
  k_embed<<<(NN * FF + 255) / 256, 256, 0, stream>>>(feat, emb, ei, s, cnt);
  k_scan<<<1, 1024, 0, stream>>>(cnt, rowst, rowcur);
  k_fillgeo<<<NE / 256, 256, 0, stream>>>(ei, pos, rowcur, d4, eid);
  k_rbf<<<NE / 256, 256, 0, stream>>>(ei, d4, eid, geo, send_s, rbf2);

  for (int b = 0; b < NBLK; b++) {
    k_phi1<<<1024, 256, 0, stream>>>(s, msgW1 + b * FF * FF, msgb1 + b * FF, h);
    k_phi2<<<1024, 256, 0, stream>>>(h, msgW2 + b * FF * 192, msgb2 + b * 192,
                                     phiUv3);
    if (b == 0)
      k_msg<true><<<2048, 256, 0, stream>>>(phiUv3, v03, s, v13,
                                            filtW + b * EB * 192,
                                            filtb + b * 192, geo, send_s,
                                            rowst, rbf2);
    else
      k_msg<false><<<2048, 256, 0, stream>>>(phiUv3, v03, s, v13,
                                             filtW + b * EB * 192,
                                             filtb + b * 192, geo, send_s,
                                             rowst, rbf2);
    k_upd1<<<1024, 256, 0, stream>>>(v13, updU + b * FF * FF, updV + b * FF * FF,
                                     phiUv3, Vn, dotUV);
    k_upd2<<<1024, 256, 0, stream>>>(s, Vn, updW1 + b * 2 * FF * FF,
                                     updb1 + b * FF, h);
    k_upd3<<<1024, 256, 0, stream>>>(h, updW2 + b * FF * 192, updb2 + b * 192,
                                     phiUv3, v13, dotUV, v03, s);
  }

  k_final<<<2048, 256, 0, stream>>>(s, roW1, rob1, roW2, rob2, gidx, rowst,
                                    send_s, gout, lap);
}

// Round 5
// 2008.134 us; speedup vs baseline: 1.0807x; 1.0807x over previous
//
#include <hip/hip_runtime.h>

#define NN 50000
#define NE 800000
#define FF 64
#define EB 20
#define NBLK 3
#define NG 100

__device__ __forceinline__ float silu_f(float x) {
  return x / (1.f + expf(-x));
}

// ---------------- init ----------------
__global__ __launch_bounds__(256) void k_init(float4* v0, int* cnt, float* gout) {
  int i = blockIdx.x * blockDim.x + threadIdx.x;
  if (i < NN * 48) v0[i] = make_float4(0.f, 0.f, 0.f, 0.f);
  if (i < NN) cnt[i] = 0;
  if (i < NG) gout[i] = 0.f;
}

// embed + recv histogram
__global__ __launch_bounds__(256) void k_embed(const int* __restrict__ feat,
                                               const float* __restrict__ emb,
                                               const int* __restrict__ ei,
                                               float* __restrict__ s, int* cnt) {
  int i = blockIdx.x * blockDim.x + threadIdx.x;
  if (i < NN * FF) s[i] = emb[feat[i >> 6] * FF + (i & 63)];
  if (i < NE) atomicAdd(&cnt[ei[i]], 1);
}

// ---------------- CSR scan ----------------
__global__ __launch_bounds__(1024) void k_scan(const int* __restrict__ cnt,
                                               int* __restrict__ rowst,
                                               int* __restrict__ rowcur) {
  __shared__ int part[1024];
  int t = threadIdx.x;
  const int CH = 52;
  int base = t * CH;
  int own = 0;
  const int4* c4 = (const int4*)(cnt + base);
#pragma unroll
  for (int i = 0; i < CH / 4; i++) {
    int idx = base + i * 4;
    if (idx + 3 < NN) {
      int4 q = c4[i];
      own += q.x + q.y + q.z + q.w;
    } else {
      for (int j = 0; j < 4; j++)
        if (idx + j < NN) own += cnt[idx + j];
    }
  }
  part[t] = own;
  __syncthreads();
  for (int off = 1; off < 1024; off <<= 1) {
    int v = (t >= off) ? part[t - off] : 0;
    __syncthreads();
    part[t] += v;
    __syncthreads();
  }
  int excl = part[t] - own;
  for (int i = 0; i < CH; i++) {
    int idx = base + i;
    if (idx < NN) {
      rowst[idx] = excl;
      rowcur[idx] = excl;
      excl += cnt[idx];
    }
  }
  if (t == 1023) rowst[NN] = excl;
}

// ---------------- edge geometry ----------------
__global__ __launch_bounds__(256) void k_fillgeo(const int* __restrict__ ei,
                                                 const float* __restrict__ pos,
                                                 int* rowcur, float4* __restrict__ d4,
                                                 int* __restrict__ eid) {
  int e = blockIdx.x * blockDim.x + threadIdx.x;
  if (e >= NE) return;
  int rv = ei[e], sd = ei[NE + e];
  float dx = pos[sd * 3 + 0] - pos[rv * 3 + 0];
  float dy = pos[sd * 3 + 1] - pos[rv * 3 + 1];
  float dz = pos[sd * 3 + 2] - pos[rv * 3 + 2];
  float r = sqrtf(dx * dx + dy * dy + dz * dz);
  d4[e] = make_float4(dx, dy, dz, r);
  int slot = atomicAdd(&rowcur[rv], 1);
  eid[slot] = e;
}

// slot-parallel: geo=(dhat,fc), send_s, rbf2[slot][k]=rbf_k*fc
__global__ __launch_bounds__(256) void k_rbf(const int* __restrict__ ei,
                                             const float4* __restrict__ d4,
                                             const int* __restrict__ eid,
                                             float4* __restrict__ geo,
                                             int* __restrict__ send_s,
                                             float* __restrict__ rbf2) {
  __shared__ float buf[256 * EB];
  int tid = threadIdx.x;
  int slot = blockIdx.x * 256 + tid;  // NE == 3125*256 exactly
  int e = eid[slot];
  float4 d = d4[e];
  float r = d.w;
  float inv = 1.f / (r + 1e-10f);
  float fc = (r < 5.0f) ? 0.5f * (cosf(0.6283185307179586f * r) + 1.f) : 0.f;
  geo[slot] = make_float4(d.x * inv, d.y * inv, d.z * inv, fc);
  send_s[slot] = ei[NE + e];
  float cs = 0.6324555320336759f * inv * fc;
#pragma unroll
  for (int k = 0; k < EB; k++)
    buf[tid * EB + k] = cs * sinf((float)(k + 1) * 0.6283185307179586f * r);
  __syncthreads();
  size_t base = (size_t)blockIdx.x * 256 * EB;
#pragma unroll
  for (int i = 0; i < EB; i++)
    rbf2[base + i * 256 + tid] = buf[i * 256 + tid];
}

// ---------------- phi = silu(s@W1+b1)@W2+b2 ----------------
__global__ __launch_bounds__(256) void k_phi1(const float* __restrict__ s,
                                              const float* __restrict__ W1,
                                              const float* __restrict__ b1,
                                              float* __restrict__ h) {
  int lane = threadIdx.x & 63;
  int gw = (blockIdx.x * blockDim.x + threadIdx.x) >> 6;
  int nw = (gridDim.x * blockDim.x) >> 6;
  float w[FF];
#pragma unroll
  for (int k = 0; k < FF; k++) w[k] = W1[k * FF + lane];
  float bb = b1[lane];
  for (int n0 = gw; n0 < NN; n0 += nw) {
    int n = __builtin_amdgcn_readfirstlane(n0);
    const float4* row = (const float4*)(s + (size_t)n * FF);
    float a0 = bb, a1 = 0.f, a2 = 0.f, a3 = 0.f;
#pragma unroll
    for (int q = 0; q < 16; q++) {
      float4 x = row[q];
      a0 = fmaf(x.x, w[4 * q], a0);
      a1 = fmaf(x.y, w[4 * q + 1], a1);
      a2 = fmaf(x.z, w[4 * q + 2], a2);
      a3 = fmaf(x.w, w[4 * q + 3], a3);
    }
    h[(size_t)n * FF + lane] = silu_f((a0 + a1) + (a2 + a3));
  }
}

__global__ __launch_bounds__(256) void k_phi2(const float* __restrict__ h,
                                              const float* __restrict__ W2,
                                              const float* __restrict__ b2,
                                              float3* __restrict__ phi3) {
  int lane = threadIdx.x & 63;
  int gw = (blockIdx.x * blockDim.x + threadIdx.x) >> 6;
  int nw = (gridDim.x * blockDim.x) >> 6;
  float w0[FF], w1[FF], w2[FF];
#pragma unroll
  for (int k = 0; k < FF; k++) {
    w0[k] = W2[k * 192 + lane];
    w1[k] = W2[k * 192 + 64 + lane];
    w2[k] = W2[k * 192 + 128 + lane];
  }
  float c0 = b2[lane], c1 = b2[64 + lane], c2 = b2[128 + lane];
  for (int n0 = gw; n0 < NN; n0 += nw) {
    int n = __builtin_amdgcn_readfirstlane(n0);
    const float4* row = (const float4*)(h + (size_t)n * FF);
    float a0 = c0, a1 = c1, a2 = c2;
#pragma unroll
    for (int q = 0; q < 16; q++) {
      float4 x = row[q];
      a0 = fmaf(x.x, w0[4 * q], a0);
      a1 = fmaf(x.x, w1[4 * q], a1);
      a2 = fmaf(x.x, w2[4 * q], a2);
      a0 = fmaf(x.y, w0[4 * q + 1], a0);
      a1 = fmaf(x.y, w1[4 * q + 1], a1);
      a2 = fmaf(x.y, w2[4 * q + 1], a2);
      a0 = fmaf(x.z, w0[4 * q + 2], a0);
      a1 = fmaf(x.z, w1[4 * q + 2], a1);
      a2 = fmaf(x.z, w2[4 * q + 2], a2);
      a0 = fmaf(x.w, w0[4 * q + 3], a0);
      a1 = fmaf(x.w, w1[4 * q + 3], a1);
      a2 = fmaf(x.w, w2[4 * q + 3], a2);
    }
    phi3[(size_t)n * FF + lane] = make_float3(a0, a1, a2);
  }
}

// ---------------- message aggregation (CSR, wave-per-node, pipelined) -------
template <bool FIRST>
__global__ __launch_bounds__(256) void k_msg(const float3* __restrict__ phi3,
                                             const float3* __restrict__ v03,
                                             float* __restrict__ s,
                                             float3* __restrict__ v13,
                                             const float* __restrict__ fW,
                                             const float* __restrict__ fb,
                                             const float4* __restrict__ geo,
                                             const int* __restrict__ send_s,
                                             const int* __restrict__ rowst,
                                             const float* __restrict__ rbf2) {
  int lane = threadIdx.x & 63;
  int gw = (blockIdx.x * blockDim.x + threadIdx.x) >> 6;
  int nw = (gridDim.x * blockDim.x) >> 6;
  float fw0[EB], fw1[EB], fw2[EB];
#pragma unroll
  for (int k = 0; k < EB; k++) {
    if (!FIRST) fw0[k] = fW[k * 192 + lane];
    fw1[k] = fW[k * 192 + 64 + lane];
    fw2[k] = fW[k * 192 + 128 + lane];
  }
  float fb0 = fb[lane], fb1 = fb[64 + lane], fb2 = fb[128 + lane];
  for (int n0 = gw; n0 < NN; n0 += nw) {
    int n = __builtin_amdgcn_readfirstlane(n0);
    int beg = rowst[n], end = rowst[n + 1];
    float accs = 0.f, av0 = 0.f, av1 = 0.f, av2 = 0.f;
    for (int base = beg; base < end; base += 64) {
      int cnt = end - base;
      if (cnt > 64) cnt = 64;
      // one coalesced load grabs the node's next <=64 neighbor indices
      int jl = (base + lane < end) ? send_s[base + lane] : 0;
      int t = 0;
      for (; t + 2 <= cnt; t += 2) {
        int sA = base + t, sB = sA + 1;
        int jA = __builtin_amdgcn_readlane(jl, t);
        int jB = __builtin_amdgcn_readlane(jl, t + 1);
        // issue ALL loads for both slots up front (pipelining)
        float4 gA = geo[sA], gB = geo[sB];
        const float4* rA = (const float4*)(rbf2 + (size_t)sA * EB);
        const float4* rB = (const float4*)(rbf2 + (size_t)sB * EB);
        float4 qa0 = rA[0], qa1 = rA[1], qa2 = rA[2], qa3 = rA[3], qa4 = rA[4];
        float4 qb0 = rB[0], qb1 = rB[1], qb2 = rB[2], qb3 = rB[3], qb4 = rB[4];
        float3 pA = phi3[(size_t)jA * FF + lane];
        float3 pB = phi3[(size_t)jB * FF + lane];
        float3 vA, vB;
        if (!FIRST) {
          vA = v03[(size_t)jA * FF + lane];
          vB = v03[(size_t)jB * FF + lane];
        }
        float rbA[EB] = {qa0.x, qa0.y, qa0.z, qa0.w, qa1.x, qa1.y, qa1.z,
                         qa1.w, qa2.x, qa2.y, qa2.z, qa2.w, qa3.x, qa3.y,
                         qa3.z, qa3.w, qa4.x, qa4.y, qa4.z, qa4.w};
        float rbB[EB] = {qb0.x, qb0.y, qb0.z, qb0.w, qb1.x, qb1.y, qb1.z,
                         qb1.w, qb2.x, qb2.y, qb2.z, qb2.w, qb3.x, qb3.y,
                         qb3.z, qb3.w, qb4.x, qb4.y, qb4.z, qb4.w};
        // slot A
        float wf1A = fb1 * gA.w, wf2A = fb2 * gA.w;
#pragma unroll
        for (int k = 0; k < EB; k++) {
          wf1A = fmaf(rbA[k], fw1[k], wf1A);
          wf2A = fmaf(rbA[k], fw2[k], wf2A);
        }
        float geA = pA.y * wf1A;
        accs = fmaf(pA.z, wf2A, accs);
        if (!FIRST) {
          float wf0A = fb0 * gA.w;
#pragma unroll
          for (int k = 0; k < EB; k++) wf0A = fmaf(rbA[k], fw0[k], wf0A);
          float gvA = pA.x * wf0A;
          av0 = fmaf(vA.x, gvA, fmaf(gA.x, geA, av0));
          av1 = fmaf(vA.y, gvA, fmaf(gA.y, geA, av1));
          av2 = fmaf(vA.z, gvA, fmaf(gA.z, geA, av2));
        } else {
          av0 = fmaf(gA.x, geA, av0);
          av1 = fmaf(gA.y, geA, av1);
          av2 = fmaf(gA.z, geA, av2);
        }
        // slot B
        float wf1B = fb1 * gB.w, wf2B = fb2 * gB.w;
#pragma unroll
        for (int k = 0; k < EB; k++) {
          wf1B = fmaf(rbB[k], fw1[k], wf1B);
          wf2B = fmaf(rbB[k], fw2[k], wf2B);
        }
        float geB = pB.y * wf1B;
        accs = fmaf(pB.z, wf2B, accs);
        if (!FIRST) {
          float wf0B = fb0 * gB.w;
#pragma unroll
          for (int k = 0; k < EB; k++) wf0B = fmaf(rbB[k], fw0[k], wf0B);
          float gvB = pB.x * wf0B;
          av0 = fmaf(vB.x, gvB, fmaf(gB.x, geB, av0));
          av1 = fmaf(vB.y, gvB, fmaf(gB.y, geB, av1));
          av2 = fmaf(vB.z, gvB, fmaf(gB.z, geB, av2));
        } else {
          av0 = fmaf(gB.x, geB, av0);
          av1 = fmaf(gB.y, geB, av1);
          av2 = fmaf(gB.z, geB, av2);
        }
      }
      for (; t < cnt; t++) {  // remainder slot
        int sA = base + t;
        int jA = __builtin_amdgcn_readlane(jl, t);
        float4 gA = geo[sA];
        const float4* rA = (const float4*)(rbf2 + (size_t)sA * EB);
        float4 qa0 = rA[0], qa1 = rA[1], qa2 = rA[2], qa3 = rA[3], qa4 = rA[4];
        float3 pA = phi3[(size_t)jA * FF + lane];
        float rbA[EB] = {qa0.x, qa0.y, qa0.z, qa0.w, qa1.x, qa1.y, qa1.z,
                         qa1.w, qa2.x, qa2.y, qa2.z, qa2.w, qa3.x, qa3.y,
                         qa3.z, qa3.w, qa4.x, qa4.y, qa4.z, qa4.w};
        float wf1A = fb1 * gA.w, wf2A = fb2 * gA.w;
#pragma unroll
        for (int k = 0; k < EB; k++) {
          wf1A = fmaf(rbA[k], fw1[k], wf1A);
          wf2A = fmaf(rbA[k], fw2[k], wf2A);
        }
        float geA = pA.y * wf1A;
        accs = fmaf(pA.z, wf2A, accs);
        if (!FIRST) {
          float wf0A = fb0 * gA.w;
#pragma unroll
          for (int k = 0; k < EB; k++) wf0A = fmaf(rbA[k], fw0[k], wf0A);
          float gvA = pA.x * wf0A;
          float3 vA = v03[(size_t)jA * FF + lane];
          av0 = fmaf(vA.x, gvA, fmaf(gA.x, geA, av0));
          av1 = fmaf(vA.y, gvA, fmaf(gA.y, geA, av1));
          av2 = fmaf(vA.z, gvA, fmaf(gA.z, geA, av2));
        } else {
          av0 = fmaf(gA.x, geA, av0);
          av1 = fmaf(gA.y, geA, av1);
          av2 = fmaf(gA.z, geA, av2);
        }
      }
    }
    s[(size_t)n * FF + lane] += accs;
    if (!FIRST) {
      float3 vo = v03[(size_t)n * FF + lane];
      v13[(size_t)n * FF + lane] =
          make_float3(vo.x + av0, vo.y + av1, vo.z + av2);
    } else {
      v13[(size_t)n * FF + lane] = make_float3(av0, av1, av2);
    }
  }
}

// ---------------- update block ----------------
__global__ __launch_bounds__(256) void k_upd1(const float3* __restrict__ v13,
                                              const float* __restrict__ U,
                                              const float* __restrict__ V,
                                              float3* __restrict__ Uv3,
                                              float* __restrict__ Vn,
                                              float* __restrict__ dotUV) {
  int lane = threadIdx.x & 63;
  int gw = (blockIdx.x * blockDim.x + threadIdx.x) >> 6;
  int nw = (gridDim.x * blockDim.x) >> 6;
  float u[FF], w[FF];
#pragma unroll
  for (int k = 0; k < FF; k++) {
    u[k] = U[k * FF + lane];
    w[k] = V[k * FF + lane];
  }
  for (int n0 = gw; n0 < NN; n0 += nw) {
    int n = __builtin_amdgcn_readfirstlane(n0);
    const float4* row = (const float4*)((const float*)v13 + (size_t)n * 192);
    float uv0 = 0, uv1 = 0, uv2 = 0, vv0 = 0, vv1 = 0, vv2 = 0;
#pragma unroll
    for (int gq = 0; gq < 16; gq++) {
      float4 A = row[3 * gq], B = row[3 * gq + 1], C = row[3 * gq + 2];
      int k = 4 * gq;
      uv0 = fmaf(A.x, u[k], uv0); vv0 = fmaf(A.x, w[k], vv0);
      uv1 = fmaf(A.y, u[k], uv1); vv1 = fmaf(A.y, w[k], vv1);
      uv2 = fmaf(A.z, u[k], uv2); vv2 = fmaf(A.z, w[k], vv2);
      uv0 = fmaf(A.w, u[k + 1], uv0); vv0 = fmaf(A.w, w[k + 1], vv0);
      uv1 = fmaf(B.x, u[k + 1], uv1); vv1 = fmaf(B.x, w[k + 1], vv1);
      uv2 = fmaf(B.y, u[k + 1], uv2); vv2 = fmaf(B.y, w[k + 1], vv2);
      uv0 = fmaf(B.z, u[k + 2], uv0); vv0 = fmaf(B.z, w[k + 2], vv0);
      uv1 = fmaf(B.w, u[k + 2], uv1); vv1 = fmaf(B.w, w[k + 2], vv1);
      uv2 = fmaf(C.x, u[k + 2], uv2); vv2 = fmaf(C.x, w[k + 2], vv2);
      uv0 = fmaf(C.y, u[k + 3], uv0); vv0 = fmaf(C.y, w[k + 3], vv0);
      uv1 = fmaf(C.z, u[k + 3], uv1); vv1 = fmaf(C.z, w[k + 3], vv1);
      uv2 = fmaf(C.w, u[k + 3], uv2); vv2 = fmaf(C.w, w[k + 3], vv2);
    }
    Uv3[(size_t)n * FF + lane] = make_float3(uv0, uv1, uv2);
    Vn[(size_t)n * FF + lane] = sqrtf(vv0 * vv0 + vv1 * vv1 + vv2 * vv2 + 1e-8f);
    dotUV[(size_t)n * FF + lane] = uv0 * vv0 + uv1 * vv1 + uv2 * vv2;
  }
}

__global__ __launch_bounds__(256) void k_upd2(const float* __restrict__ s,
                                              const float* __restrict__ Vn,
                                              const float* __restrict__ W1,
                                              const float* __restrict__ b1,
                                              float* __restrict__ h) {
  int lane = threadIdx.x & 63;
  int gw = (blockIdx.x * blockDim.x + threadIdx.x) >> 6;
  int nw = (gridDim.x * blockDim.x) >> 6;
  float w[2 * FF];
#pragma unroll
  for (int k = 0; k < 2 * FF; k++) w[k] = W1[k * FF + lane];
  float bb = b1[lane];
  for (int n0 = gw; n0 < NN; n0 += nw) {
    int n = __builtin_amdgcn_readfirstlane(n0);
    const float4* rs = (const float4*)(s + (size_t)n * FF);
    const float4* rv = (const float4*)(Vn + (size_t)n * FF);
    float a0 = bb, a1 = 0.f, a2 = 0.f, a3 = 0.f;
#pragma unroll
    for (int q = 0; q < 16; q++) {
      float4 x = rs[q];
      a0 = fmaf(x.x, w[4 * q], a0);
      a1 = fmaf(x.y, w[4 * q + 1], a1);
      a2 = fmaf(x.z, w[4 * q + 2], a2);
      a3 = fmaf(x.w, w[4 * q + 3], a3);
    }
#pragma unroll
    for (int q = 0; q < 16; q++) {
      float4 x = rv[q];
      a0 = fmaf(x.x, w[FF + 4 * q], a0);
      a1 = fmaf(x.y, w[FF + 4 * q + 1], a1);
      a2 = fmaf(x.z, w[FF + 4 * q + 2], a2);
      a3 = fmaf(x.w, w[FF + 4 * q + 3], a3);
    }
    h[(size_t)n * FF + lane] = silu_f((a0 + a1) + (a2 + a3));
  }
}

__global__ __launch_bounds__(256) void k_upd3(const float* __restrict__ h,
                                              const float* __restrict__ W2,
                                              const float* __restrict__ b2,
                                              const float3* __restrict__ Uv3,
                                              const float3* __restrict__ v13,
                                              const float* __restrict__ dotUV,
                                              float3* __restrict__ v03,
                                              float* __restrict__ s) {
  int lane = threadIdx.x & 63;
  int gw = (blockIdx.x * blockDim.x + threadIdx.x) >> 6;
  int nw = (gridDim.x * blockDim.x) >> 6;
  float w0[FF], w1[FF], w2[FF];
#pragma unroll
  for (int k = 0; k < FF; k++) {
    w0[k] = W2[k * 192 + lane];
    w1[k] = W2[k * 192 + 64 + lane];
    w2[k] = W2[k * 192 + 128 + lane];
  }
  float c0 = b2[lane], c1 = b2[64 + lane], c2 = b2[128 + lane];
  for (int n0 = gw; n0 < NN; n0 += nw) {
    int n = __builtin_amdgcn_readfirstlane(n0);
    const float4* row = (const float4*)(h + (size_t)n * FF);
    float a0 = c0, a1 = c1, a2 = c2;
#pragma unroll
    for (int q = 0; q < 16; q++) {
      float4 x = row[q];
      a0 = fmaf(x.x, w0[4 * q], a0);
      a1 = fmaf(x.x, w1[4 * q], a1);
      a2 = fmaf(x.x, w2[4 * q], a2);
      a0 = fmaf(x.y, w0[4 * q + 1], a0);
      a1 = fmaf(x.y, w1[4 * q + 1], a1);
      a2 = fmaf(x.y, w2[4 * q + 1], a2);
      a0 = fmaf(x.z, w0[4 * q + 2], a0);
      a1 = fmaf(x.z, w1[4 * q + 2], a1);
      a2 = fmaf(x.z, w2[4 * q + 2], a2);
      a0 = fmaf(x.w, w0[4 * q + 3], a0);
      a1 = fmaf(x.w, w1[4 * q + 3], a1);
      a2 = fmaf(x.w, w2[4 * q + 3], a2);
    }
    float3 uv = Uv3[(size_t)n * FF + lane];
    float3 vv = v13[(size_t)n * FF + lane];
    v03[(size_t)n * FF + lane] = make_float3(
        fmaf(a0, uv.x, vv.x), fmaf(a0, uv.y, vv.y), fmaf(a0, uv.z, vv.z));
    size_t i_ = (size_t)n * FF + lane;
    s[i_] = fmaf(a1, dotUV[i_], s[i_] + a2);
  }
}

// ---------------- fused readout + graph sum + laplacian (pipelined) --------
__global__ __launch_bounds__(256) void k_final(const float* __restrict__ s,
                                               const float* __restrict__ roW1,
                                               const float* __restrict__ rob1,
                                               const float* __restrict__ roW2,
                                               const float* __restrict__ rob2,
                                               const int* __restrict__ gidx,
                                               const int* __restrict__ rowst,
                                               const int* __restrict__ send_s,
                                               float* __restrict__ gout,
                                               float* __restrict__ lap) {
  int lane = threadIdx.x & 63;
  int gw = (blockIdx.x * blockDim.x + threadIdx.x) >> 6;
  int nw = (gridDim.x * blockDim.x) >> 6;
  float w[FF];
#pragma unroll
  for (int k = 0; k < FF; k++) w[k] = roW1[k * FF + lane];
  float b1v = rob1[lane], w2v = roW2[lane], b2v = rob2[0];
  for (int n0 = gw; n0 < NN; n0 += nw) {
    int n = __builtin_amdgcn_readfirstlane(n0);
    int beg = rowst[n], end = rowst[n + 1];
    float ac0 = 0.f, ac1 = 0.f, ac2 = 0.f, ac3 = 0.f;
    float ac4 = 0.f, ac5 = 0.f, ac6 = 0.f, ac7 = 0.f;
    for (int base = beg; base < end; base += 64) {
      int cnt = end - base;
      if (cnt > 64) cnt = 64;
      int jl = (base + lane < end) ? send_s[base + lane] : 0;
      int t = 0;
      for (; t + 8 <= cnt; t += 8) {
        int j0 = __builtin_amdgcn_readlane(jl, t);
        int j1 = __builtin_amdgcn_readlane(jl, t + 1);
        int j2 = __builtin_amdgcn_readlane(jl, t + 2);
        int j3 = __builtin_amdgcn_readlane(jl, t + 3);
        int j4 = __builtin_amdgcn_readlane(jl, t + 4);
        int j5 = __builtin_amdgcn_readlane(jl, t + 5);
        int j6 = __builtin_amdgcn_readlane(jl, t + 6);
        int j7 = __builtin_amdgcn_readlane(jl, t + 7);
        ac0 += s[(size_t)j0 * FF + lane];
        ac1 += s[(size_t)j1 * FF + lane];
        ac2 += s[(size_t)j2 * FF + lane];
        ac3 += s[(size_t)j3 * FF + lane];
        ac4 += s[(size_t)j4 * FF + lane];
        ac5 += s[(size_t)j5 * FF + lane];
        ac6 += s[(size_t)j6 * FF + lane];
        ac7 += s[(size_t)j7 * FF + lane];
      }
      for (; t < cnt; t++) {
        int j0 = __builtin_amdgcn_readlane(jl, t);
        ac0 += s[(size_t)j0 * FF + lane];
      }
    }
    float acc = ((ac0 + ac1) + (ac2 + ac3)) + ((ac4 + ac5) + (ac6 + ac7));
    float sv = s[(size_t)n * FF + lane];
    lap[(size_t)n * FF + lane] = (float)(end - beg) * sv - acc;
    const float4* row = (const float4*)(s + (size_t)n * FF);
    float a0 = b1v, a1 = 0.f, a2 = 0.f, a3 = 0.f;
#pragma unroll
    for (int q = 0; q < 16; q++) {
      float4 x = row[q];
      a0 = fmaf(x.x, w[4 * q], a0);
      a1 = fmaf(x.y, w[4 * q + 1], a1);
      a2 = fmaf(x.z, w[4 * q + 2], a2);
      a3 = fmaf(x.w, w[4 * q + 3], a3);
    }
    float c = silu_f((a0 + a1) + (a2 + a3)) * w2v;
#pragma unroll
    for (int off = 32; off > 0; off >>= 1) c += __shfl_down(c, off, 64);
    if (lane == 0) atomicAdd(&gout[gidx[n]], c + b2v);
  }
}

extern "C" void kernel_launch(void* const* d_in, const int* in_sizes, int n_in,
                              void* d_out, int out_size, void* d_ws, size_t ws_size,
                              hipStream_t stream) {
  const int* feat = (const int*)d_in[0];
  const float* pos = (const float*)d_in[1];
  const int* ei = (const int*)d_in[2];
  const int* gidx = (const int*)d_in[3];
  const float* emb = (const float*)d_in[4];
  const float* msgW1 = (const float*)d_in[5];
  const float* msgb1 = (const float*)d_in[6];
  const float* msgW2 = (const float*)d_in[7];
  const float* msgb2 = (const float*)d_in[8];
  const float* filtW = (const float*)d_in[9];
  const float* filtb = (const float*)d_in[10];
  const float* updU = (const float*)d_in[11];
  const float* updV = (const float*)d_in[12];
  const float* updW1 = (const float*)d_in[13];
  const float* updb1 = (const float*)d_in[14];
  const float* updW2 = (const float*)d_in[15];
  const float* updb2 = (const float*)d_in[16];
  const float* roW1 = (const float*)d_in[17];
  const float* rob1 = (const float*)d_in[18];
  const float* roW2 = (const float*)d_in[19];
  const float* rob2 = (const float*)d_in[20];

  float* gout = (float*)d_out;
  float* s = gout + NG;
  float* lap = s + (size_t)NN * FF;

  char* p = (char*)d_ws;
  auto alloc = [&](size_t bytes) {
    char* r = p;
    p += (bytes + 255) & ~(size_t)255;
    return r;
  };
  float3* v03 = (float3*)alloc((size_t)NN * 192 * 4);
  float3* v13 = (float3*)alloc((size_t)NN * 192 * 4);
  float3* phiUv3 = (float3*)alloc((size_t)NN * 192 * 4);  // phi, reused as Uv
  float* h = (float*)alloc((size_t)NN * FF * 4);
  float* Vn = (float*)alloc((size_t)NN * FF * 4);
  float* dotUV = (float*)alloc((size_t)NN * FF * 4);
  float4* geo = (float4*)alloc((size_t)NE * 16);
  float4* d4 = (float4*)alloc((size_t)NE * 16);
  float* rbf2 = (float*)alloc((size_t)NE * EB * 4);
  int* send_s = (int*)alloc((size_t)NE * 4);
  int* eid = (int*)alloc((size_t)NE * 4);
  int* rowst = (int*)alloc((size_t)(NN + 1) * 4);
  int* rowcur = (int*)alloc((size_t)NN * 4);
  int* cnt = (int*)alloc((size_t)NN * 4);

  k_init<<<(NN * 48 + 255) / 256, 256, 0, stream>>>((float4*)v03, cnt, gout);
  k_embed<<<(NN * FF + 255) / 256, 256, 0, stream>>>(feat, emb, ei, s, cnt);
  k_scan<<<1, 1024, 0, stream>>>(cnt, rowst, rowcur);
  k_fillgeo<<<NE / 256, 256, 0, stream>>>(ei, pos, rowcur, d4, eid);
  k_rbf<<<NE / 256, 256, 0, stream>>>(ei, d4, eid, geo, send_s, rbf2);

  for (int b = 0; b < NBLK; b++) {
    k_phi1<<<1024, 256, 0, stream>>>(s, msgW1 + b * FF * FF, msgb1 + b * FF, h);
    k_phi2<<<1024, 256, 0, stream>>>(h, msgW2 + b * FF * 192, msgb2 + b * 192,
                                     phiUv3);
    if (b == 0)
      k_msg<true><<<4096, 256, 0, stream>>>(phiUv3, v03, s, v13,
                                            filtW + b * EB * 192,
                                            filtb + b * 192, geo, send_s,
                                            rowst, rbf2);
    else
      k_msg<false><<<4096, 256, 0, stream>>>(phiUv3, v03, s, v13,
                                             filtW + b * EB * 192,
                                             filtb + b * 192, geo, send_s,
                                             rowst, rbf2);
    k_upd1<<<1024, 256, 0, stream>>>(v13, updU + b * FF * FF, updV + b * FF * FF,
                                     phiUv3, Vn, dotUV);
    k_upd2<<<1024, 256, 0, stream>>>(s, Vn, updW1 + b * 2 * FF * FF,
                                     updb1 + b * FF, h);
    k_upd3<<<1024, 256, 0, stream>>>(h, updW2 + b * FF * 192, updb2 + b * 192,
                                     phiUv3, v13, dotUV, v03, s);
  }

  k_final<<<4096, 256, 0, stream>>>(s, roW1, rob1, roW2, rob2, gidx, rowst,
                                    send_s, gout, lap);
}